// Round 2
// baseline (2030.796 us; speedup 1.0000x reference)
//
#include <hip/hip_runtime.h>
#include <hip/hip_bf16.h>

constexpr int S   = 10;
constexpr int Bsz = 16384;
constexpr int LAG = 5;
constexpr int H   = 512;
constexpr int G4  = 4 * H;            // 2048
constexpr int F   = 5;
constexpr int BH  = Bsz * H;          // 8388608
constexpr int OUT_HN = Bsz * (S + F); // 245760
constexpr int OUT_CN = OUT_HN + 2 * BH;

// GEMM tile geometry
constexpr int BM   = 256;             // batch rows per block
constexpr int UN   = 32;              // hidden units per block
constexpr int BN   = 4 * UN;          // 128 N-cols (4 gates x 32 units)
constexpr int BK   = 64;              // K per tile (128B rows, XOR-8 swizzle)
constexpr int NBUF = 3;               // depth-2 prefetch pipeline
constexpr int A_TILE = BM * BK;       // 16384 shorts = 32 KB
constexpr int B_TILE = BN * BK;       // 8192 shorts = 16 KB

typedef __attribute__((ext_vector_type(8))) short short8;   // 8 bf16 = 4 VGPRs
typedef __attribute__((ext_vector_type(4))) float f32x4;

__device__ __forceinline__ float sigf(float x) { return 1.0f / (1.0f + __expf(-x)); }
__device__ __forceinline__ float tanh_fast(float x) {
    float e = __expf(2.0f * x);
    return 1.0f - 2.0f / (e + 1.0f);
}

__device__ __forceinline__ void gload_lds16(const void* g, void* l) {
    __builtin_amdgcn_global_load_lds(
        (const __attribute__((address_space(1))) unsigned int*)g,
        (__attribute__((address_space(3))) unsigned int*)l, 16, 0, 0);
}

// ---------------------------------------------------------------------------
// Prep (gate-major):
//   W0b = bf16(Whh0) [2048,512];  W1b = bf16([Wih1 | Whh1]) [2048,1024]
//   A0r = Wih0 @ W_in [2048,5];   b0 = Wih0@b_in + bih0 + bhh0;  b1 = bih1+bhh1
// ---------------------------------------------------------------------------
__global__ __launch_bounds__(256)
void prep_kernel(const float* __restrict__ W_in,  const float* __restrict__ b_in,
                 const float* __restrict__ Wih0,  const float* __restrict__ Whh0,
                 const float* __restrict__ bih0,  const float* __restrict__ bhh0,
                 const float* __restrict__ Wih1,  const float* __restrict__ Whh1,
                 const float* __restrict__ bih1,  const float* __restrict__ bhh1,
                 __hip_bfloat16* __restrict__ W0b, __hip_bfloat16* __restrict__ W1b,
                 float* __restrict__ A0r, float* __restrict__ b0r,
                 float* __restrict__ b1r)
{
    const int r   = blockIdx.x;   // 0..2047, gate-major (PyTorch order)
    const int tid = threadIdx.x;

    for (int k = tid; k < H; k += 256)
        W0b[r * H + k] = __float2bfloat16(Whh0[r * H + k]);
    for (int k = tid; k < 2 * H; k += 256)
        W1b[r * 2 * H + k] = __float2bfloat16(
            (k < H) ? Wih1[r * H + k] : Whh1[r * H + (k - H)]);

    if (tid < LAG) {
        float s = 0.f;
        for (int h = 0; h < H; ++h) s += Wih0[r * H + h] * W_in[h * LAG + tid];
        A0r[r * LAG + tid] = s;
    } else if (tid == 5) {
        float s = 0.f;
        for (int h = 0; h < H; ++h) s += Wih0[r * H + h] * b_in[h];
        b0r[r] = s + bih0[r] + bhh0[r];
    } else if (tid == 6) {
        b1r[r] = bih1[r] + bhh1[r];
    }
}

// ---------------------------------------------------------------------------
// MFMA GEMM + fused LSTM cell. 256x128 tile, 8 waves (4M x 2N), BK=64,
// static 151.5 KB LDS, 3-buffer pipeline with counted vmcnt (depth-2),
// raw s_barrier, setprio around MFMA, XCD-aware bijective block swizzle.
// LDS rows: 8x16B chunks, chunk j stored from source chunk j^(row&7)
// (source-side swizzle; global_load_lds dest stays linear) — proven
// conflict-free geometry from the previous working kernel.
// ---------------------------------------------------------------------------
__global__ __launch_bounds__(512, 2)
void lstm_gemm(const __hip_bfloat16* __restrict__ Aseg0,
               const __hip_bfloat16* __restrict__ Aseg1,
               int nseg,                                  // 0, 1 or 2
               const __hip_bfloat16* __restrict__ W, int ldw,
               const float* __restrict__ bias,
               const float* __restrict__ xs,   // [B,5] or null
               const float* __restrict__ A0r,  // [2048,5] or null
               const float* __restrict__ c_in, // null => c_old = 0
               float* __restrict__ c_out,
               float* __restrict__ h32_out,    // fp32 h_n slot or null
               __hip_bfloat16* __restrict__ hb16_out, // bf16 h concat buffer
               int hcol)                       // 0 (layer0) or 512 (layer1)
{
    __shared__ __align__(16) short As[NBUF * A_TILE];   // 96 KB
    __shared__ __align__(16) short Bs[NBUF * B_TILE];   // 48 KB
    __shared__ float xls[BM * LAG];                     // 5 KB
    __shared__ float a0ls[BN * LAG];                    // 2.5 KB

    const int tid  = threadIdx.x;
    const int lane = tid & 63;
    const int quad = lane >> 4;
    const int li   = lane & 15;
    const int wv   = tid >> 6;       // 0..7
    const int wy   = wv >> 1;        // 0..3  (M quarter, 64 rows)
    const int wx   = wv & 1;         // 0..1  (unit half, 16 units x 4 gates)

    // XCD-aware bijective swizzle: 1024 blocks, each XCD gets 128 contiguous
    // (by,bx) pairs = 8 batch panels x all 16 unit blocks -> A L2-reuse.
    const int l  = blockIdx.y * gridDim.x + blockIdx.x;   // 0..1023
    const int v  = (l & 7) * 128 + (l >> 3);
    const int by = v >> 4;                        // 0..63 batch block
    const int bx = v & 15;                        // 0..15 unit block
    const int bM_ = by * BM;
    const int cn  = bx * UN;

    const bool has_x = (xs != nullptr);
    if (has_x) {
        for (int i = tid; i < BM * LAG; i += 512) {
            const int row = i / LAG, ll = i % LAG;
            xls[i] = xs[(size_t)(bM_ + row) * LAG + ll];
        }
        for (int i = tid; i < BN * LAG; i += 512) {
            const int cl = i / LAG, ll = i % LAG;
            const int r  = (cl >> 5) * H + cn + (cl & 31);
            a0ls[i] = A0r[r * LAG + ll];
        }
    }
    __syncthreads();

    f32x4 acc[4][4];  // [m-frag][gate]
    #pragma unroll
    for (int i = 0; i < 4; ++i)
        #pragma unroll
        for (int j = 0; j < 4; ++j) acc[i][j] = (f32x4){0.f, 0.f, 0.f, 0.f};

    // staging geometry: per thread 4 A-chunks + 2 B-chunks (16B each) per tile.
    // source column chunk is XOR-swizzled; LDS dest linear.
    int aoff[4], woff[2];
    #pragma unroll
    for (int r = 0; r < 4; ++r) {
        const int idx = r * 512 + tid;            // 0..2047
        const int row = idx >> 3;                 // 0..255
        const int j   = idx & 7;
        aoff[r] = (bM_ + row) * 1024 + ((j ^ (row & 7)) * 8);
    }
    #pragma unroll
    for (int r = 0; r < 2; ++r) {
        const int idx = r * 512 + tid;            // 0..1023
        const int row = idx >> 3;                 // 0..127  (gate*32+unit)
        const int j   = idx & 7;
        const int rr  = (row >> 5) * H + cn + (row & 31);
        woff[r] = rr * ldw + ((j ^ (row & 7)) * 8);
    }

    const int NT = nseg * 8;                      // K-tiles of 64

    auto stage_tile = [&](int t) {
        const int seg = t >> 3;
        const int kof = seg * 512 + (t & 7) * BK;    // = t*64 overall
        const short* pa = (const short*)(seg ? Aseg1 : Aseg0) + kof;
        const short* pw = (const short*)W + kof;
        short* as = As + (t % NBUF) * A_TILE;
        short* bs = Bs + (t % NBUF) * B_TILE;
        #pragma unroll
        for (int r = 0; r < 4; ++r)
            gload_lds16(pa + aoff[r], &as[(r * 512 + tid) * 8]);
        #pragma unroll
        for (int r = 0; r < 2; ++r)
            gload_lds16(pw + woff[r], &bs[(r * 512 + tid) * 8]);
    };

    auto compute_tile = [&](int t) {
        const short* as = As + (t % NBUF) * A_TILE;
        const short* bs = Bs + (t % NBUF) * B_TILE;
        #pragma unroll
        for (int c = 0; c < 2; ++c) {
            const int p = (c * 4 + quad) ^ (li & 7);   // physical chunk
            short8 af[4], bf[4];
            #pragma unroll
            for (int m = 0; m < 4; ++m)
                af[m] = *(const short8*)&as[(wy * 64 + m * 16 + li) * 64 + p * 8];
            #pragma unroll
            for (int g = 0; g < 4; ++g)
                bf[g] = *(const short8*)&bs[(g * 32 + wx * 16 + li) * 64 + p * 8];
            __builtin_amdgcn_s_setprio(1);
            #pragma unroll
            for (int m = 0; m < 4; ++m)
                #pragma unroll
                for (int g = 0; g < 4; ++g)
                    acc[m][g] = __builtin_amdgcn_mfma_f32_16x16x32_bf16(
                        af[m], bf[g], acc[m][g], 0, 0, 0);
            __builtin_amdgcn_s_setprio(0);
        }
    };

    if (NT) {
        stage_tile(0);
        stage_tile(1);
        for (int t = 0; t < NT - 1; ++t) {
            // counted vmcnt: 6 loads/tile; tile t+1 (6 loads) stays in flight
            // across the raw barrier (no compiler drain).
            asm volatile("s_waitcnt vmcnt(6)\n\ts_barrier" ::: "memory");
            if (t + 2 < NT) stage_tile(t + 2);   // writes buf (t-1)%3: all
                                                 // waves done reading it
            compute_tile(t);
        }
        asm volatile("s_waitcnt vmcnt(0)\n\ts_barrier" ::: "memory");
        compute_tile(NT - 1);
    }

    // ---------------- epilogue: bias + x-fold + LSTM cell ----------------
    const int n = cn + wx * 16 + li;        // this lane's hidden unit
    float bias4[4], a0reg[4][LAG];
    #pragma unroll
    for (int g = 0; g < 4; ++g) bias4[g] = bias[g * H + n];
    if (has_x) {
        #pragma unroll
        for (int g = 0; g < 4; ++g)
            #pragma unroll
            for (int ll = 0; ll < LAG; ++ll)
                a0reg[g][ll] = a0ls[(g * 32 + wx * 16 + li) * LAG + ll];
    }

    #pragma unroll
    for (int mt = 0; mt < 4; ++mt) {
        #pragma unroll
        for (int reg = 0; reg < 4; ++reg) {
            const int b_loc = wy * 64 + mt * 16 + quad * 4 + reg;
            const int b     = bM_ + b_loc;
            float g4[4];
            #pragma unroll
            for (int g = 0; g < 4; ++g) g4[g] = acc[mt][g][reg] + bias4[g];
            if (has_x) {
                #pragma unroll
                for (int ll = 0; ll < LAG; ++ll) {
                    const float xv = xls[b_loc * LAG + ll];
                    #pragma unroll
                    for (int g = 0; g < 4; ++g) g4[g] = fmaf(xv, a0reg[g][ll], g4[g]);
                }
            }
            const float ig = sigf(g4[0]);
            const float fg = sigf(g4[1]);
            const float gg = tanh_fast(g4[2]);
            const float og = sigf(g4[3]);
            const float cold = c_in ? c_in[(size_t)b * H + n] : 0.f;
            const float cnew = fg * cold + ig * gg;
            const float hh   = og * tanh_fast(cnew);
            c_out[(size_t)b * H + n] = cnew;
            if (h32_out) h32_out[(size_t)b * H + n] = hh;
            hb16_out[(size_t)b * 1024 + hcol + n] = __float2bfloat16(hh);
        }
    }
}

// ---------------------------------------------------------------------------
// Per-step scalar head (+ forecast head on last step). One wave per row.
// Reads bf16 h1 from hcat (cols 512..1023).
// ---------------------------------------------------------------------------
__global__ __launch_bounds__(256)
void out_head(const __hip_bfloat16* __restrict__ hcat,
              const float* __restrict__ W_out, const float* __restrict__ b_out,
              const float* __restrict__ W_f,   const float* __restrict__ b_f,
              float* __restrict__ out, int s, int last)
{
    const int wave = threadIdx.x >> 6;
    const int lane = threadIdx.x & 63;
    const int b    = blockIdx.x * 4 + wave;

    const __hip_bfloat16* hrow = hcat + (size_t)b * 1024 + 512;
    short8 hv = *(const short8*)&hrow[lane * 8];
    float h8[8];
    #pragma unroll
    for (int i = 0; i < 8; ++i) {
        union { unsigned int u; float f; } cv;
        cv.u = ((unsigned int)(unsigned short)hv[i]) << 16;
        h8[i] = cv.f;
    }

    {
        const float4 w0 = *reinterpret_cast<const float4*>(&W_out[lane * 8]);
        const float4 w1 = *reinterpret_cast<const float4*>(&W_out[lane * 8 + 4]);
        const float w8[8] = {w0.x, w0.y, w0.z, w0.w, w1.x, w1.y, w1.z, w1.w};
        float v = 0.f;
        #pragma unroll
        for (int i = 0; i < 8; ++i) v = fmaf(h8[i], w8[i], v);
        #pragma unroll
        for (int off = 32; off > 0; off >>= 1) v += __shfl_down(v, off, 64);
        if (lane == 0) out[b * (S + F) + s] = v + b_out[0];
    }
    if (last) {
        for (int f = 0; f < F; ++f) {
            const float4 w0 = *reinterpret_cast<const float4*>(&W_f[f * H + lane * 8]);
            const float4 w1 = *reinterpret_cast<const float4*>(&W_f[f * H + lane * 8 + 4]);
            const float w8[8] = {w0.x, w0.y, w0.z, w0.w, w1.x, w1.y, w1.z, w1.w};
            float v = 0.f;
            #pragma unroll
            for (int i = 0; i < 8; ++i) v = fmaf(h8[i], w8[i], v);
            #pragma unroll
            for (int off = 32; off > 0; off >>= 1) v += __shfl_down(v, off, 64);
            if (lane == 0) out[b * (S + F) + S + f] = v + b_f[f];
        }
    }
}

// ---------------------------------------------------------------------------
extern "C" void kernel_launch(void* const* d_in, const int* in_sizes, int n_in,
                              void* d_out, int out_size, void* d_ws, size_t ws_size,
                              hipStream_t stream)
{
    const float* x     = (const float*)d_in[0];
    const float* W_in  = (const float*)d_in[1];
    const float* b_in  = (const float*)d_in[2];
    const float* Wih0  = (const float*)d_in[3];
    const float* Whh0  = (const float*)d_in[4];
    const float* bih0  = (const float*)d_in[5];
    const float* bhh0  = (const float*)d_in[6];
    const float* Wih1  = (const float*)d_in[7];
    const float* Whh1  = (const float*)d_in[8];
    const float* bih1  = (const float*)d_in[9];
    const float* bhh1  = (const float*)d_in[10];
    const float* W_out = (const float*)d_in[11];
    const float* b_out = (const float*)d_in[12];
    const float* W_f   = (const float*)d_in[13];
    const float* b_f   = (const float*)d_in[14];

    float* out = (float*)d_out;
    char*  ws  = (char*)d_ws;

    // workspace layout
    __hip_bfloat16* hcat0 = (__hip_bfloat16*)ws;                    // [B,1024]
    __hip_bfloat16* hcat1 = hcat0 + (size_t)Bsz * 1024;             // [B,1024]
    __hip_bfloat16* W0b   = hcat1 + (size_t)Bsz * 1024;             // [2048,512]
    __hip_bfloat16* W1b   = W0b + (size_t)G4 * H;                   // [2048,1024]
    float* A0r = (float*)(W1b + (size_t)G4 * 2 * H);                // [2048,5]
    float* b0r = A0r + G4 * LAG;
    float* b1r = b0r + G4;

    // d_out sections as state
    float* hn0 = out + OUT_HN;            // h0 fp32 (last step only)
    float* hn1 = out + OUT_HN + BH;       // h1 fp32 (last step only)
    float* c0  = out + OUT_CN;            // c0 in place
    float* c1  = out + OUT_CN + BH;       // c1 in place

    prep_kernel<<<dim3(G4), dim3(256), 0, stream>>>(
        W_in, b_in, Wih0, Whh0, bih0, bhh0, Wih1, Whh1, bih1, bhh1,
        W0b, W1b, A0r, b0r, b1r);

    __hip_bfloat16* hbuf[2] = {hcat0, hcat1};
    const dim3 grid(H / UN, Bsz / BM);   // (16, 64) = 1024 blocks
    const dim3 blk(512);

    for (int s = 0; s < S; ++s) {
        const bool first = (s == 0);
        const bool last  = (s == S - 1);
        __hip_bfloat16* cur  = hbuf[s & 1];
        __hip_bfloat16* prev = hbuf[(s + 1) & 1];

        // layer 0: A = h0_prev (cols 0-511 of prev), K=512
        lstm_gemm<<<grid, blk, 0, stream>>>(
            prev, nullptr, first ? 0 : 1, W0b, H, b0r,
            x + (size_t)s * Bsz * LAG, A0r,
            first ? nullptr : c0, c0, last ? hn0 : nullptr, cur, 0);

        // layer 1: A = [h0_cur cols 0-511 | h1_prev cols 512-1023], K=1024
        lstm_gemm<<<grid, blk, 0, stream>>>(
            cur, prev, first ? 1 : 2, W1b, 2 * H, b1r,
            nullptr, nullptr,
            first ? nullptr : c1, c1, last ? hn1 : nullptr, cur, H);

        out_head<<<dim3(Bsz / 4), dim3(256), 0, stream>>>(
            cur, W_out, b_out, W_f, b_f, out, s, last ? 1 : 0);
    }
}

// Round 3
// 1847.787 us; speedup vs baseline: 1.0990x; 1.0990x over previous
//
#include <hip/hip_runtime.h>
#include <hip/hip_bf16.h>

constexpr int S   = 10;
constexpr int Bsz = 16384;
constexpr int LAG = 5;
constexpr int H   = 512;
constexpr int G4  = 4 * H;            // 2048
constexpr int F   = 5;
constexpr int BH  = Bsz * H;          // 8388608
constexpr int OUT_HN = Bsz * (S + F); // 245760
constexpr int OUT_CN = OUT_HN + 2 * BH;

// GEMM tile geometry: 128 batch x (4 gates x 32 units), TK=32 half-tiles,
// 2-buffer LDS pipeline. 256 threads, 4 waves (2M x 2N). 37 KB LDS ->
// 4 blocks/CU co-resident (the round-0 occupancy that worked).
constexpr int TK   = 32;
constexpr int NBUF = 2;
constexpr int A_T  = 128 * TK;        // 4096 shorts = 8 KB per buffer
constexpr int B_T  = 128 * TK;        // 4096 shorts = 8 KB per buffer

typedef __attribute__((ext_vector_type(8))) short short8;   // 8 bf16 = 4 VGPRs
typedef __attribute__((ext_vector_type(4))) float f32x4;

__device__ __forceinline__ float sigf(float x) { return 1.0f / (1.0f + __expf(-x)); }
__device__ __forceinline__ float tanh_fast(float x) {
    float e = __expf(2.0f * x);
    return 1.0f - 2.0f / (e + 1.0f);
}

__device__ __forceinline__ void gload_lds16(const void* g, void* l) {
    __builtin_amdgcn_global_load_lds(
        (const __attribute__((address_space(1))) unsigned int*)g,
        (__attribute__((address_space(3))) unsigned int*)l, 16, 0, 0);
}

// ---------------------------------------------------------------------------
// Prep (gate-major):
//   W0b = bf16(Whh0) [2048,512];  W1b = bf16([Wih1 | Whh1]) [2048,1024]
//   A0r = Wih0 @ W_in [2048,5];   b0 = Wih0@b_in + bih0 + bhh0;  b1 = bih1+bhh1
// ---------------------------------------------------------------------------
__global__ __launch_bounds__(256)
void prep_kernel(const float* __restrict__ W_in,  const float* __restrict__ b_in,
                 const float* __restrict__ Wih0,  const float* __restrict__ Whh0,
                 const float* __restrict__ bih0,  const float* __restrict__ bhh0,
                 const float* __restrict__ Wih1,  const float* __restrict__ Whh1,
                 const float* __restrict__ bih1,  const float* __restrict__ bhh1,
                 __hip_bfloat16* __restrict__ W0b, __hip_bfloat16* __restrict__ W1b,
                 float* __restrict__ A0r, float* __restrict__ b0r,
                 float* __restrict__ b1r)
{
    const int r   = blockIdx.x;   // 0..2047, gate-major (PyTorch order)
    const int tid = threadIdx.x;

    for (int k = tid; k < H; k += 256)
        W0b[r * H + k] = __float2bfloat16(Whh0[r * H + k]);
    for (int k = tid; k < 2 * H; k += 256)
        W1b[r * 2 * H + k] = __float2bfloat16(
            (k < H) ? Wih1[r * H + k] : Whh1[r * H + (k - H)]);

    if (tid < LAG) {
        float s = 0.f;
        for (int h = 0; h < H; ++h) s += Wih0[r * H + h] * W_in[h * LAG + tid];
        A0r[r * LAG + tid] = s;
    } else if (tid == 5) {
        float s = 0.f;
        for (int h = 0; h < H; ++h) s += Wih0[r * H + h] * b_in[h];
        b0r[r] = s + bih0[r] + bhh0[r];
    } else if (tid == 6) {
        b1r[r] = bih1[r] + bhh1[r];
    }
}

// ---------------------------------------------------------------------------
// MFMA GEMM + fused LSTM cell. 128x128 tile, 4 waves (2x2), TK=32 half-tiles,
// 2-buffer pipeline: stage(t+1) BEFORE compute(t), single vmcnt(0)+s_barrier
// AFTER compute (T3-minimum 2-phase: load latency hides under MFMA).
// LDS rows are 64 B -> natural 2-way bank aliasing only (free); everything
// linear (global_load_lds dest = base + lane*16).
// ---------------------------------------------------------------------------
__global__ __launch_bounds__(256)
void lstm_gemm(const __hip_bfloat16* __restrict__ Aseg0,
               const __hip_bfloat16* __restrict__ Aseg1,
               int nseg,                                  // 0, 1 or 2
               const __hip_bfloat16* __restrict__ W, int ldw,
               const float* __restrict__ bias,
               const float* __restrict__ xs,   // [B,5] or null
               const float* __restrict__ A0r,  // [2048,5] or null
               const float* __restrict__ c_in, // null => c_old = 0
               float* __restrict__ c_out,
               float* __restrict__ h32_out,    // fp32 h_n slot or null
               __hip_bfloat16* __restrict__ hb16_out, // bf16 h concat buffer
               int hcol)                       // 0 (layer0) or 512 (layer1)
{
    __shared__ __align__(16) short As[NBUF * A_T];   // 16 KB
    __shared__ __align__(16) short Bs[NBUF * B_T];   // 16 KB
    __shared__ float xls[128 * LAG];                 // 2.5 KB
    __shared__ float a0ls[128 * LAG];                // 2.5 KB

    const int tid  = threadIdx.x;
    const int lane = tid & 63;
    const int quad = lane >> 4;
    const int li   = lane & 15;
    const int wv   = tid >> 6;       // 0..3
    const int wy   = wv >> 1;        // 0..1  (M half, 64 rows)
    const int wx   = wv & 1;         // 0..1  (unit half, 16 units x 4 gates)

    // XCD-aware bijective swizzle: 2048 blocks = 8 x 256; each XCD gets
    // 16 contiguous batch panels x all 16 unit blocks -> A-panel L2 reuse.
    const int l  = blockIdx.y * gridDim.x + blockIdx.x;   // 0..2047
    const int v  = (l & 7) * 256 + (l >> 3);
    const int by = v >> 4;                        // 0..127 batch block
    const int bx = v & 15;                        // 0..15  unit block
    const int bM_ = by * 128;
    const int cn  = bx * 32;

    const bool has_x = (xs != nullptr);
    if (has_x) {
        for (int i = tid; i < 128 * LAG; i += 256) {
            const int row = i / LAG, ll = i % LAG;
            xls[i] = xs[(size_t)(bM_ + row) * LAG + ll];
        }
        for (int i = tid; i < 128 * LAG; i += 256) {
            const int cl = i / LAG, ll = i % LAG;      // cl = g*32+nn
            const int r  = (cl >> 5) * H + cn + (cl & 31);
            a0ls[i] = A0r[r * LAG + ll];
        }
        __syncthreads();
    }

    f32x4 acc[4][4];  // [m-frag][gate]
    #pragma unroll
    for (int i = 0; i < 4; ++i)
        #pragma unroll
        for (int j = 0; j < 4; ++j) acc[i][j] = (f32x4){0.f, 0.f, 0.f, 0.f};

    // staging geometry: per thread 2 A-chunks + 2 B-chunks (16 B) per half-tile
    int a_off[2], w_off[2];
    #pragma unroll
    for (int r = 0; r < 2; ++r) {
        const int idx = r * 256 + tid;            // 0..511
        const int row = idx >> 2;                 // 0..127
        const int j   = idx & 3;                  // 16B chunk in 64B row
        a_off[r] = (bM_ + row) * 1024 + j * 8;    // hcat row stride = 1024
        const int rr = (row >> 5) * H + cn + (row & 31);   // gate-major W row
        w_off[r] = rr * ldw + j * 8;
    }

    const int NT = nseg * 16;                     // half-tiles of K=32

    auto stage_tile = [&](int t) {
        const int seg = t >> 4;
        const int kof = seg * 512 + (t & 15) * TK;   // = t*32 overall (shorts)
        const short* pa = (const short*)(seg ? Aseg1 : Aseg0) + kof;
        const short* pw = (const short*)W + kof;
        short* as = As + (t & 1) * A_T;
        short* bs = Bs + (t & 1) * B_T;
        #pragma unroll
        for (int r = 0; r < 2; ++r) {
            const int idx = r * 256 + tid;
            gload_lds16(pa + a_off[r], &as[idx * 8]);
            gload_lds16(pw + w_off[r], &bs[idx * 8]);
        }
    };

    auto compute_tile = [&](int t) {
        const short* as = As + (t & 1) * A_T;
        const short* bs = Bs + (t & 1) * B_T;
        short8 af[4], bf[4];
        #pragma unroll
        for (int m = 0; m < 4; ++m)
            af[m] = *(const short8*)&as[(wy * 64 + m * 16 + li) * TK + quad * 8];
        #pragma unroll
        for (int g = 0; g < 4; ++g)
            bf[g] = *(const short8*)&bs[(g * 32 + wx * 16 + li) * TK + quad * 8];
        #pragma unroll
        for (int m = 0; m < 4; ++m)
            #pragma unroll
            for (int g = 0; g < 4; ++g)
                acc[m][g] = __builtin_amdgcn_mfma_f32_16x16x32_bf16(
                    af[m], bf[g], acc[m][g], 0, 0, 0);
    };

    if (NT) {
        stage_tile(0);
        asm volatile("s_waitcnt vmcnt(0)\n\ts_barrier" ::: "memory");
        for (int t = 0; t < NT; ++t) {
            if (t + 1 < NT) stage_tile(t + 1);   // issue next loads FIRST
            compute_tile(t);                     // MFMA hides their latency
            asm volatile("s_waitcnt vmcnt(0)\n\ts_barrier" ::: "memory");
        }
    }

    // ---------------- epilogue: bias + x-fold + LSTM cell ----------------
    const int n = cn + wx * 16 + li;        // this lane's hidden unit
    float bias4[4], a0reg[4][LAG];
    #pragma unroll
    for (int g = 0; g < 4; ++g) bias4[g] = bias[g * H + n];
    if (has_x) {
        #pragma unroll
        for (int g = 0; g < 4; ++g)
            #pragma unroll
            for (int ll = 0; ll < LAG; ++ll)
                a0reg[g][ll] = a0ls[(g * 32 + wx * 16 + li) * LAG + ll];
    }

    #pragma unroll
    for (int mt = 0; mt < 4; ++mt) {
        #pragma unroll
        for (int reg = 0; reg < 4; ++reg) {
            const int b_loc = wy * 64 + mt * 16 + quad * 4 + reg;
            const int b     = bM_ + b_loc;
            float g4[4];
            #pragma unroll
            for (int g = 0; g < 4; ++g) g4[g] = acc[mt][g][reg] + bias4[g];
            if (has_x) {
                #pragma unroll
                for (int ll = 0; ll < LAG; ++ll) {
                    const float xv = xls[b_loc * LAG + ll];
                    #pragma unroll
                    for (int g = 0; g < 4; ++g) g4[g] = fmaf(xv, a0reg[g][ll], g4[g]);
                }
            }
            const float ig = sigf(g4[0]);
            const float fg = sigf(g4[1]);
            const float gg = tanh_fast(g4[2]);
            const float og = sigf(g4[3]);
            const float cold = c_in ? c_in[(size_t)b * H + n] : 0.f;
            const float cnew = fg * cold + ig * gg;
            const float hh   = og * tanh_fast(cnew);
            c_out[(size_t)b * H + n] = cnew;
            if (h32_out) h32_out[(size_t)b * H + n] = hh;
            hb16_out[(size_t)b * 1024 + hcol + n] = __float2bfloat16(hh);
        }
    }
}

// ---------------------------------------------------------------------------
// Per-step scalar head (+ forecast head on last step). One wave per row.
// Reads bf16 h1 from hcat (cols 512..1023).
// ---------------------------------------------------------------------------
__global__ __launch_bounds__(256)
void out_head(const __hip_bfloat16* __restrict__ hcat,
              const float* __restrict__ W_out, const float* __restrict__ b_out,
              const float* __restrict__ W_f,   const float* __restrict__ b_f,
              float* __restrict__ out, int s, int last)
{
    const int wave = threadIdx.x >> 6;
    const int lane = threadIdx.x & 63;
    const int b    = blockIdx.x * 4 + wave;

    const __hip_bfloat16* hrow = hcat + (size_t)b * 1024 + 512;
    short8 hv = *(const short8*)&hrow[lane * 8];
    float h8[8];
    #pragma unroll
    for (int i = 0; i < 8; ++i) {
        union { unsigned int u; float f; } cv;
        cv.u = ((unsigned int)(unsigned short)hv[i]) << 16;
        h8[i] = cv.f;
    }

    {
        const float4 w0 = *reinterpret_cast<const float4*>(&W_out[lane * 8]);
        const float4 w1 = *reinterpret_cast<const float4*>(&W_out[lane * 8 + 4]);
        const float w8[8] = {w0.x, w0.y, w0.z, w0.w, w1.x, w1.y, w1.z, w1.w};
        float v = 0.f;
        #pragma unroll
        for (int i = 0; i < 8; ++i) v = fmaf(h8[i], w8[i], v);
        #pragma unroll
        for (int off = 32; off > 0; off >>= 1) v += __shfl_down(v, off, 64);
        if (lane == 0) out[b * (S + F) + s] = v + b_out[0];
    }
    if (last) {
        for (int f = 0; f < F; ++f) {
            const float4 w0 = *reinterpret_cast<const float4*>(&W_f[f * H + lane * 8]);
            const float4 w1 = *reinterpret_cast<const float4*>(&W_f[f * H + lane * 8 + 4]);
            const float w8[8] = {w0.x, w0.y, w0.z, w0.w, w1.x, w1.y, w1.z, w1.w};
            float v = 0.f;
            #pragma unroll
            for (int i = 0; i < 8; ++i) v = fmaf(h8[i], w8[i], v);
            #pragma unroll
            for (int off = 32; off > 0; off >>= 1) v += __shfl_down(v, off, 64);
            if (lane == 0) out[b * (S + F) + S + f] = v + b_f[f];
        }
    }
}

// ---------------------------------------------------------------------------
extern "C" void kernel_launch(void* const* d_in, const int* in_sizes, int n_in,
                              void* d_out, int out_size, void* d_ws, size_t ws_size,
                              hipStream_t stream)
{
    const float* x     = (const float*)d_in[0];
    const float* W_in  = (const float*)d_in[1];
    const float* b_in  = (const float*)d_in[2];
    const float* Wih0  = (const float*)d_in[3];
    const float* Whh0  = (const float*)d_in[4];
    const float* bih0  = (const float*)d_in[5];
    const float* bhh0  = (const float*)d_in[6];
    const float* Wih1  = (const float*)d_in[7];
    const float* Whh1  = (const float*)d_in[8];
    const float* bih1  = (const float*)d_in[9];
    const float* bhh1  = (const float*)d_in[10];
    const float* W_out = (const float*)d_in[11];
    const float* b_out = (const float*)d_in[12];
    const float* W_f   = (const float*)d_in[13];
    const float* b_f   = (const float*)d_in[14];

    float* out = (float*)d_out;
    char*  ws  = (char*)d_ws;

    // workspace layout
    __hip_bfloat16* hcat0 = (__hip_bfloat16*)ws;                    // [B,1024]
    __hip_bfloat16* hcat1 = hcat0 + (size_t)Bsz * 1024;             // [B,1024]
    __hip_bfloat16* W0b   = hcat1 + (size_t)Bsz * 1024;             // [2048,512]
    __hip_bfloat16* W1b   = W0b + (size_t)G4 * H;                   // [2048,1024]
    float* A0r = (float*)(W1b + (size_t)G4 * 2 * H);                // [2048,5]
    float* b0r = A0r + G4 * LAG;
    float* b1r = b0r + G4;

    // d_out sections as state
    float* hn0 = out + OUT_HN;            // h0 fp32 (last step only)
    float* hn1 = out + OUT_HN + BH;       // h1 fp32 (last step only)
    float* c0  = out + OUT_CN;            // c0 in place
    float* c1  = out + OUT_CN + BH;       // c1 in place

    prep_kernel<<<dim3(G4), dim3(256), 0, stream>>>(
        W_in, b_in, Wih0, Whh0, bih0, bhh0, Wih1, Whh1, bih1, bhh1,
        W0b, W1b, A0r, b0r, b1r);

    __hip_bfloat16* hbuf[2] = {hcat0, hcat1};
    const dim3 grid(16, 128);   // 2048 blocks
    const dim3 blk(256);

    for (int s = 0; s < S; ++s) {
        const bool first = (s == 0);
        const bool last  = (s == S - 1);
        __hip_bfloat16* cur  = hbuf[s & 1];
        __hip_bfloat16* prev = hbuf[(s + 1) & 1];

        // layer 0: A = h0_prev (cols 0-511 of prev), K=512
        lstm_gemm<<<grid, blk, 0, stream>>>(
            prev, nullptr, first ? 0 : 1, W0b, H, b0r,
            x + (size_t)s * Bsz * LAG, A0r,
            first ? nullptr : c0, c0, last ? hn0 : nullptr, cur, 0);

        // layer 1: A = [h0_cur cols 0-511 | h1_prev cols 512-1023], K=1024
        lstm_gemm<<<grid, blk, 0, stream>>>(
            cur, prev, first ? 1 : 2, W1b, 2 * H, b1r,
            nullptr, nullptr,
            first ? nullptr : c1, c1, last ? hn1 : nullptr, cur, H);

        out_head<<<dim3(Bsz / 4), dim3(256), 0, stream>>>(
            cur, W_out, b_out, W_f, b_f, out, s, last ? 1 : 0);
    }
}